// Round 1
// baseline (556.186 us; speedup 1.0000x reference)
//
#include <hip/hip_runtime.h>

// Problem constants (verified against in_sizes at launch where cheap).
#define HDIM 64

// ---------------- kernels ----------------

__global__ void k_deg(const int* __restrict__ row, float* __restrict__ deg, int E) {
    int e = blockIdx.x * blockDim.x + threadIdx.x;
    if (e < E) atomicAdd(&deg[row[e]], 1.0f);
}

__global__ void k_dis(const float* __restrict__ deg, float* __restrict__ dis, int n) {
    int i = blockIdx.x * blockDim.x + threadIdx.x;
    if (i < n) {
        float d = deg[i];
        dis[i] = d > 0.0f ? rsqrtf(d) : 0.0f;
    }
}

// Scatter 1: Tx1[col][:] += w_e * x[row][:]   (w_e = -dis[row]*dis[col])
// One edge per 64-lane group; 4 edges per 256-thread block.
__global__ __launch_bounds__(256) void k_scatter1(const int* __restrict__ row,
                                                  const int* __restrict__ col,
                                                  const float* __restrict__ dis,
                                                  const float* __restrict__ x,
                                                  float* __restrict__ Tx, int E) {
    int e = blockIdx.x * 4 + (threadIdx.x >> 6);
    if (e >= E) return;
    int lane = threadIdx.x & 63;
    int r = row[e], c = col[e];
    float w = -dis[r] * dis[c];
    atomicAdd(&Tx[(size_t)c * HDIM + lane], w * x[(size_t)r * HDIM + lane]);
}

// h = x@W1[0] + Tx1@W1[1] + b1, written in-place over Tx1 (block-local rows).
__global__ __launch_bounds__(256) void k_gemm1(const float* __restrict__ x,
                                               float* __restrict__ TxH,
                                               const float* __restrict__ W1,
                                               const float* __restrict__ b1, int n) {
    __shared__ float Ws[2 * HDIM * HDIM];       // 32 KB
    __shared__ float xs[4][HDIM];
    __shared__ float ts[4][HDIM];
    int tid = threadIdx.x;
    for (int idx = tid; idx < 2 * HDIM * HDIM; idx += 256) Ws[idx] = W1[idx];

    int rr = tid >> 6;           // 0..3
    int j  = tid & 63;
    int r  = blockIdx.x * 4 + rr;
    if (r < n) {
        xs[rr][j] = x[(size_t)r * HDIM + j];
        ts[rr][j] = TxH[(size_t)r * HDIM + j];
    }
    __syncthreads();
    if (r >= n) return;
    float acc = b1[j];
    const float* w0 = Ws;
    const float* w1 = Ws + HDIM * HDIM;
    #pragma unroll 8
    for (int k = 0; k < HDIM; ++k) {
        acc = fmaf(xs[rr][k], w0[k * HDIM + j], acc);
        acc = fmaf(ts[rr][k], w1[k * HDIM + j], acc);
    }
    TxH[(size_t)r * HDIM + j] = acc;
}

// Column sums / sums of squares over h (N x 64) -> stats[0:64]=sum, stats[64:128]=sumsq
__global__ __launch_bounds__(256) void k_stats(const float* __restrict__ h,
                                               float* __restrict__ stats, int n) {
    int j  = threadIdx.x & 63;
    int rg = threadIdx.x >> 6;   // 0..3
    float s = 0.f, ss = 0.f;
    for (int r = blockIdx.x * 4 + rg; r < n; r += gridDim.x * 4) {
        float v = h[(size_t)r * HDIM + j];
        s += v;
        ss = fmaf(v, v, ss);
    }
    __shared__ float red[2][4][HDIM];
    red[0][rg][j] = s;
    red[1][rg][j] = ss;
    __syncthreads();
    if (rg == 0) {
        s  = red[0][0][j] + red[0][1][j] + red[0][2][j] + red[0][3][j];
        ss = red[1][0][j] + red[1][1][j] + red[1][2][j] + red[1][3][j];
        atomicAdd(&stats[j], s);
        atomicAdd(&stats[64 + j], ss);
    }
}

// BN scale/shift, u0 = W2[0]@linW, u1 = W2[1]@linW, c0 = b2.linW + linb
__global__ void k_prep(const float* __restrict__ stats,
                       const float* __restrict__ gamma, const float* __restrict__ beta,
                       const float* __restrict__ W2, const float* __restrict__ b2,
                       const float* __restrict__ linW, const float* __restrict__ linb,
                       float* __restrict__ scale, float* __restrict__ shift,
                       float* __restrict__ u0, float* __restrict__ u1,
                       float* __restrict__ c0, int n) {
    int k = threadIdx.x;
    if (k >= HDIM) return;
    float inv_n = 1.0f / (float)n;
    float mu  = stats[k] * inv_n;
    float var = stats[64 + k] * inv_n - mu * mu;
    float rs  = rsqrtf(var + 1e-5f);
    float sc  = rs * gamma[k];
    scale[k] = sc;
    shift[k] = beta[k] - mu * sc;
    float a0 = 0.f, a1 = 0.f;
    #pragma unroll 8
    for (int j = 0; j < HDIM; ++j) {
        float lw = linW[j];
        a0 = fmaf(W2[k * HDIM + j], lw, a0);
        a1 = fmaf(W2[HDIM * HDIM + k * HDIM + j], lw, a1);
    }
    u0[k] = a0;
    u1[k] = a1;
    if (k == 0) {
        float c = linb[0];
        for (int j = 0; j < HDIM; ++j) c = fmaf(b2[j], linW[j], c);
        c0[0] = c;
    }
}

// Per node: BN + LeakyReLU, then a[i]=y.u0, t[i]=y.u1 (wave-wide shuffle reduce).
__global__ __launch_bounds__(256) void k_node(const float* __restrict__ h,
                                              const float* __restrict__ scale,
                                              const float* __restrict__ shift,
                                              const float* __restrict__ u0,
                                              const float* __restrict__ u1,
                                              float* __restrict__ a, float* __restrict__ t,
                                              int n) {
    int i = blockIdx.x * 4 + (threadIdx.x >> 6);
    if (i >= n) return;
    int j = threadIdx.x & 63;
    float v = fmaf(h[(size_t)i * HDIM + j], scale[j], shift[j]);
    v = v >= 0.f ? v : 0.01f * v;
    float p0 = v * u0[j];
    float p1 = v * u1[j];
    #pragma unroll
    for (int off = 32; off > 0; off >>= 1) {
        p0 += __shfl_xor(p0, off, 64);
        p1 += __shfl_xor(p1, off, 64);
    }
    if (j == 0) { a[i] = p0; t[i] = p1; }
}

// Scalar scatter 2: s2[col] += w_e * t[row]
__global__ void k_scatter2(const int* __restrict__ row, const int* __restrict__ col,
                           const float* __restrict__ dis, const float* __restrict__ t,
                           float* __restrict__ s2, int E) {
    int e = blockIdx.x * blockDim.x + threadIdx.x;
    if (e < E) {
        int r = row[e], c = col[e];
        atomicAdd(&s2[c], -dis[r] * dis[c] * t[r]);
    }
}

__global__ void k_pool(const float* __restrict__ a, const float* __restrict__ s2,
                       const int* __restrict__ batch,
                       float* __restrict__ gsum, float* __restrict__ gcnt, int n) {
    int i = blockIdx.x * blockDim.x + threadIdx.x;
    if (i < n) {
        int g = batch[i];
        atomicAdd(&gsum[g], a[i] + s2[i]);
        atomicAdd(&gcnt[g], 1.0f);
    }
}

__global__ void k_out(const float* __restrict__ gsum, const float* __restrict__ gcnt,
                      const float* __restrict__ c0, float* __restrict__ out, int g) {
    int i = blockIdx.x * blockDim.x + threadIdx.x;
    if (i < g) out[i] = gsum[i] / fmaxf(gcnt[i], 1.0f) + c0[0];
}

// ---------------- launch ----------------

extern "C" void kernel_launch(void* const* d_in, const int* in_sizes, int n_in,
                              void* d_out, int out_size, void* d_ws, size_t ws_size,
                              hipStream_t stream) {
    const float* x     = (const float*)d_in[0];
    const int*   eidx  = (const int*)d_in[1];
    const int*   batch = (const int*)d_in[2];
    const float* W1    = (const float*)d_in[3];
    const float* b1    = (const float*)d_in[4];
    const float* W2    = (const float*)d_in[5];
    const float* b2    = (const float*)d_in[6];
    const float* gamma = (const float*)d_in[7];
    const float* beta  = (const float*)d_in[8];
    const float* linW  = (const float*)d_in[9];
    const float* linb  = (const float*)d_in[10];
    float* out = (float*)d_out;

    const int N = in_sizes[0] / HDIM;       // 50000
    const int E = in_sizes[1] / 2;          // 800000
    const int G = out_size;                 // 100

    const int* row = eidx;
    const int* col = eidx + E;

    // workspace layout (floats)
    float* ws = (float*)d_ws;
    size_t off = 0;
    float* deg   = ws + off; off += N;
    float* dis   = ws + off; off += N;
    float* TxH   = ws + off; off += (size_t)N * HDIM;   // Tx1 then h in-place
    float* a     = ws + off; off += N;
    float* t     = ws + off; off += N;
    float* s2    = ws + off; off += N;
    float* stats = ws + off; off += 128;
    float* scale = ws + off; off += HDIM;
    float* shift = ws + off; off += HDIM;
    float* u0    = ws + off; off += HDIM;
    float* u1    = ws + off; off += HDIM;
    float* c0    = ws + off; off += 1;
    float* gsum  = ws + off; off += G;
    float* gcnt  = ws + off; off += G;

    // zero everything we accumulate into (deg, TxH, s2, stats, gsum, gcnt).
    hipMemsetAsync(d_ws, 0, off * sizeof(float), stream);

    k_deg<<<(E + 255) / 256, 256, 0, stream>>>(row, deg, E);
    k_dis<<<(N + 255) / 256, 256, 0, stream>>>(deg, dis, N);
    k_scatter1<<<(E + 3) / 4, 256, 0, stream>>>(row, col, dis, x, TxH, E);
    k_gemm1<<<(N + 3) / 4, 256, 0, stream>>>(x, TxH, W1, b1, N);
    k_stats<<<256, 256, 0, stream>>>(TxH, stats, N);
    k_prep<<<1, 64, 0, stream>>>(stats, gamma, beta, W2, b2, linW, linb,
                                 scale, shift, u0, u1, c0, N);
    k_node<<<(N + 3) / 4, 256, 0, stream>>>(TxH, scale, shift, u0, u1, a, t, N);
    k_scatter2<<<(E + 255) / 256, 256, 0, stream>>>(row, col, dis, t, s2, E);
    k_pool<<<(N + 255) / 256, 256, 0, stream>>>(a, s2, batch, gsum, gcnt, N);
    k_out<<<(G + 127) / 128, 128, 0, stream>>>(gsum, gcnt, c0, out, G);
}

// Round 2
// 276.154 us; speedup vs baseline: 2.0140x; 2.0140x over previous
//
#include <hip/hip_runtime.h>

#define HDIM 64

// ---------------- small helpers ----------------

__device__ __forceinline__ int lbound(const int* __restrict__ b, int n, int v) {
    int lo = 0, hi = n;
    while (lo < hi) { int m = (lo + hi) >> 1; if (b[m] < v) lo = m + 1; else hi = m; }
    return lo;
}

// ---------------- kernels ----------------

// Histogram: deg by row (for norm), cnt by col (for CSR).
__global__ void k_hist(const int* __restrict__ row, const int* __restrict__ col,
                       int* __restrict__ deg, int* __restrict__ cnt, int E) {
    int e = blockIdx.x * blockDim.x + threadIdx.x;
    if (e < E) {
        atomicAdd(&deg[row[e]], 1);
        atomicAdd(&cnt[col[e]], 1);
    }
}

__global__ void k_dis(const int* __restrict__ deg, float* __restrict__ dis, int n) {
    int i = blockIdx.x * blockDim.x + threadIdx.x;
    if (i < n) {
        int d = deg[i];
        dis[i] = d > 0 ? rsqrtf((float)d) : 0.0f;
    }
}

// Exclusive scan of cnt, 2-level. Level 1: per-1024 block scan.
__global__ __launch_bounds__(1024) void k_scan1(const int* __restrict__ cnt,
                                                int* __restrict__ start,
                                                int* __restrict__ bsum, int n) {
    __shared__ int sh[1024];
    int i = blockIdx.x * 1024 + threadIdx.x;
    int v = (i < n) ? cnt[i] : 0;
    sh[threadIdx.x] = v;
    __syncthreads();
    for (int off = 1; off < 1024; off <<= 1) {
        int t = 0;
        if (threadIdx.x >= off) t = sh[threadIdx.x - off];
        __syncthreads();
        sh[threadIdx.x] += t;
        __syncthreads();
    }
    if (i < n) start[i] = sh[threadIdx.x] - v;   // exclusive within block
    if (threadIdx.x == 1023) bsum[blockIdx.x] = sh[1023];
}

__global__ void k_scan2(int* __restrict__ bsum, int nb) {
    if (blockIdx.x == 0 && threadIdx.x == 0) {
        int acc = 0;
        for (int b = 0; b < nb; ++b) { int v = bsum[b]; bsum[b] = acc; acc += v; }
    }
}

__global__ void k_scan3(int* __restrict__ start, const int* __restrict__ bsum, int n) {
    int i = blockIdx.x * blockDim.x + threadIdx.x;
    if (i < n) start[i] += bsum[i >> 10];
}

// Fill CSR: er[start[c] + cursor] = row(e)
__global__ void k_fill(const int* __restrict__ row, const int* __restrict__ col,
                       const int* __restrict__ start, int* __restrict__ cur,
                       int* __restrict__ er, int E) {
    int e = blockIdx.x * blockDim.x + threadIdx.x;
    if (e < E) {
        int c = col[e];
        int p = atomicAdd(&cur[c], 1);
        er[start[c] + p] = row[e];
    }
}

// Gather 1: Tx[i][:] = sum over in-edges of (-dis[r]*dis[i]) * x[r][:]
// One 64-lane wave per node.
__global__ __launch_bounds__(256) void k_gather1(const int* __restrict__ er,
                                                 const int* __restrict__ start,
                                                 const int* __restrict__ cnt,
                                                 const float* __restrict__ dis,
                                                 const float* __restrict__ x,
                                                 float* __restrict__ Tx, int n) {
    int i = blockIdx.x * 4 + (threadIdx.x >> 6);
    if (i >= n) return;
    int lane = threadIdx.x & 63;
    int s = start[i], nd = cnt[i];
    float di = dis[i];
    float acc = 0.f;
    int k = 0;
    for (; k + 1 < nd; k += 2) {          // 2-way unroll for load ILP
        int r0 = er[s + k], r1 = er[s + k + 1];
        float w0 = -dis[r0] * di, w1 = -dis[r1] * di;
        float v0 = x[(size_t)r0 * HDIM + lane];
        float v1 = x[(size_t)r1 * HDIM + lane];
        acc = fmaf(w0, v0, acc);
        acc = fmaf(w1, v1, acc);
    }
    if (k < nd) {
        int r0 = er[s + k];
        acc = fmaf(-dis[r0] * di, x[(size_t)r0 * HDIM + lane], acc);
    }
    Tx[(size_t)i * HDIM + lane] = acc;
}

// h = x@W1[0] + Tx1@W1[1] + b1, in-place over Tx1 (rows are block-local).
__global__ __launch_bounds__(256) void k_gemm1(const float* __restrict__ x,
                                               float* __restrict__ TxH,
                                               const float* __restrict__ W1,
                                               const float* __restrict__ b1, int n) {
    __shared__ float Ws[2 * HDIM * HDIM];       // 32 KB
    __shared__ float xs[4][HDIM];
    __shared__ float ts[4][HDIM];
    int tid = threadIdx.x;
    for (int idx = tid; idx < 2 * HDIM * HDIM; idx += 256) Ws[idx] = W1[idx];

    int rr = tid >> 6;
    int j  = tid & 63;
    int r  = blockIdx.x * 4 + rr;
    if (r < n) {
        xs[rr][j] = x[(size_t)r * HDIM + j];
        ts[rr][j] = TxH[(size_t)r * HDIM + j];
    }
    __syncthreads();
    if (r >= n) return;
    float acc = b1[j];
    const float* w0 = Ws;
    const float* w1 = Ws + HDIM * HDIM;
    #pragma unroll 8
    for (int k = 0; k < HDIM; ++k) {
        acc = fmaf(xs[rr][k], w0[k * HDIM + j], acc);
        acc = fmaf(ts[rr][k], w1[k * HDIM + j], acc);
    }
    TxH[(size_t)r * HDIM + j] = acc;
}

// Column sums / sums of squares over h (N x 64)
__global__ __launch_bounds__(256) void k_stats(const float* __restrict__ h,
                                               float* __restrict__ stats, int n) {
    int j  = threadIdx.x & 63;
    int rg = threadIdx.x >> 6;
    float s = 0.f, ss = 0.f;
    for (int r = blockIdx.x * 4 + rg; r < n; r += gridDim.x * 4) {
        float v = h[(size_t)r * HDIM + j];
        s += v;
        ss = fmaf(v, v, ss);
    }
    __shared__ float red[2][4][HDIM];
    red[0][rg][j] = s;
    red[1][rg][j] = ss;
    __syncthreads();
    if (rg == 0) {
        s  = red[0][0][j] + red[0][1][j] + red[0][2][j] + red[0][3][j];
        ss = red[1][0][j] + red[1][1][j] + red[1][2][j] + red[1][3][j];
        atomicAdd(&stats[j], s);
        atomicAdd(&stats[64 + j], ss);
    }
}

// BN scale/shift, u0 = W2[0]@linW, u1 = W2[1]@linW, c0 = b2.linW + linb
__global__ void k_prep(const float* __restrict__ stats,
                       const float* __restrict__ gamma, const float* __restrict__ beta,
                       const float* __restrict__ W2, const float* __restrict__ b2,
                       const float* __restrict__ linW, const float* __restrict__ linb,
                       float* __restrict__ scale, float* __restrict__ shift,
                       float* __restrict__ u0, float* __restrict__ u1,
                       float* __restrict__ c0, int n) {
    int k = threadIdx.x;
    if (k >= HDIM) return;
    float inv_n = 1.0f / (float)n;
    float mu  = stats[k] * inv_n;
    float var = stats[64 + k] * inv_n - mu * mu;
    float rs  = rsqrtf(var + 1e-5f);
    float sc  = rs * gamma[k];
    scale[k] = sc;
    shift[k] = beta[k] - mu * sc;
    float a0 = 0.f, a1 = 0.f;
    #pragma unroll 8
    for (int j = 0; j < HDIM; ++j) {
        float lw = linW[j];
        a0 = fmaf(W2[k * HDIM + j], lw, a0);
        a1 = fmaf(W2[HDIM * HDIM + k * HDIM + j], lw, a1);
    }
    u0[k] = a0;
    u1[k] = a1;
    if (k == 0) {
        float c = linb[0];
        for (int j = 0; j < HDIM; ++j) c = fmaf(b2[j], linW[j], c);
        c0[0] = c;
    }
}

// Per node: BN + LeakyReLU, a[i]=y.u0, t[i]=y.u1 (wave shuffle reduce).
__global__ __launch_bounds__(256) void k_node(const float* __restrict__ h,
                                              const float* __restrict__ scale,
                                              const float* __restrict__ shift,
                                              const float* __restrict__ u0,
                                              const float* __restrict__ u1,
                                              float* __restrict__ a, float* __restrict__ t,
                                              int n) {
    int i = blockIdx.x * 4 + (threadIdx.x >> 6);
    if (i >= n) return;
    int j = threadIdx.x & 63;
    float v = fmaf(h[(size_t)i * HDIM + j], scale[j], shift[j]);
    v = v >= 0.f ? v : 0.01f * v;
    float p0 = v * u0[j];
    float p1 = v * u1[j];
    #pragma unroll
    for (int off = 32; off > 0; off >>= 1) {
        p0 += __shfl_xor(p0, off, 64);
        p1 += __shfl_xor(p1, off, 64);
    }
    if (j == 0) { a[i] = p0; t[i] = p1; }
}

// Gather 2 (scalar): s2[i] = a[i] + sum over in-edges of (-dis[r]*dis[i]) * t[r]
__global__ void k_gather2(const int* __restrict__ er, const int* __restrict__ start,
                          const int* __restrict__ cnt, const float* __restrict__ dis,
                          const float* __restrict__ t, const float* __restrict__ a,
                          float* __restrict__ s2, int n) {
    int i = blockIdx.x * blockDim.x + threadIdx.x;
    if (i >= n) return;
    int s = start[i], nd = cnt[i];
    float di = dis[i];
    float acc = a[i];
    int k = 0;
    for (; k + 1 < nd; k += 2) {
        int r0 = er[s + k], r1 = er[s + k + 1];
        float v0 = -dis[r0] * di * t[r0];
        float v1 = -dis[r1] * di * t[r1];
        acc += v0 + v1;
    }
    if (k < nd) {
        int r0 = er[s + k];
        acc = fmaf(-dis[r0] * di, t[r0], acc);
    }
    s2[i] = acc;
}

// Pool: one block per graph; batch is sorted -> binary search the range.
__global__ __launch_bounds__(256) void k_pool2(const float* __restrict__ s2,
                                               const int* __restrict__ batch,
                                               const float* __restrict__ c0,
                                               const float* __restrict__ linb,
                                               float* __restrict__ out, int n) {
    int g = blockIdx.x;
    int lo = lbound(batch, n, g);
    int hi = lbound(batch, n, g + 1);
    float s = 0.f;
    for (int i = lo + threadIdx.x; i < hi; i += 256) s += s2[i];
    __shared__ float red[256];
    red[threadIdx.x] = s;
    __syncthreads();
    for (int off = 128; off > 0; off >>= 1) {
        if (threadIdx.x < off) red[threadIdx.x] += red[threadIdx.x + off];
        __syncthreads();
    }
    if (threadIdx.x == 0) {
        int cntg = hi - lo;
        out[g] = cntg > 0 ? red[0] / (float)cntg + c0[0] : linb[0];
    }
}

// ---------------- launch ----------------

extern "C" void kernel_launch(void* const* d_in, const int* in_sizes, int n_in,
                              void* d_out, int out_size, void* d_ws, size_t ws_size,
                              hipStream_t stream) {
    const float* x     = (const float*)d_in[0];
    const int*   eidx  = (const int*)d_in[1];
    const int*   batch = (const int*)d_in[2];
    const float* W1    = (const float*)d_in[3];
    const float* b1    = (const float*)d_in[4];
    const float* W2    = (const float*)d_in[5];
    const float* b2    = (const float*)d_in[6];
    const float* gamma = (const float*)d_in[7];
    const float* beta  = (const float*)d_in[8];
    const float* linW  = (const float*)d_in[9];
    const float* linb  = (const float*)d_in[10];
    float* out = (float*)d_out;

    const int N = in_sizes[0] / HDIM;       // 50000
    const int E = in_sizes[1] / 2;          // 800000
    const int G = out_size;                 // 100
    const int NB = (N + 1023) / 1024;       // scan blocks

    const int* row = eidx;
    const int* col = eidx + E;

    // ---- workspace layout ----
    // zero-required region first: deg(N int) | cnt(N int) | cur(N int) | stats(128 f)
    char* wsb = (char*)d_ws;
    int*   deg   = (int*)wsb;                 wsb += (size_t)N * 4;
    int*   cnt   = (int*)wsb;                 wsb += (size_t)N * 4;
    int*   cur   = (int*)wsb;                 wsb += (size_t)N * 4;
    float* stats = (float*)wsb;               wsb += 128 * 4;
    size_t zero_bytes = (size_t)wsb - (size_t)d_ws;
    int*   start = (int*)wsb;                 wsb += (size_t)N * 4;
    int*   bsum  = (int*)wsb;                 wsb += (size_t)NB * 4 + 64;
    int*   er    = (int*)wsb;                 wsb += (size_t)E * 4;
    float* dis   = (float*)wsb;               wsb += (size_t)N * 4;
    float* a     = (float*)wsb;               wsb += (size_t)N * 4;
    float* t     = (float*)wsb;               wsb += (size_t)N * 4;
    float* s2    = (float*)wsb;               wsb += (size_t)N * 4;
    float* TxH   = (float*)wsb;               wsb += (size_t)N * HDIM * 4;
    float* scale = (float*)wsb;               wsb += HDIM * 4;
    float* shift = (float*)wsb;               wsb += HDIM * 4;
    float* u0    = (float*)wsb;               wsb += HDIM * 4;
    float* u1    = (float*)wsb;               wsb += HDIM * 4;
    float* c0    = (float*)wsb;               wsb += 64;

    hipMemsetAsync(d_ws, 0, zero_bytes, stream);

    k_hist<<<(E + 255) / 256, 256, 0, stream>>>(row, col, deg, cnt, E);
    k_dis<<<(N + 255) / 256, 256, 0, stream>>>(deg, dis, N);
    k_scan1<<<NB, 1024, 0, stream>>>(cnt, start, bsum, N);
    k_scan2<<<1, 64, 0, stream>>>(bsum, NB);
    k_scan3<<<(N + 255) / 256, 256, 0, stream>>>(start, bsum, N);
    k_fill<<<(E + 255) / 256, 256, 0, stream>>>(row, col, start, cur, er, E);
    k_gather1<<<(N + 3) / 4, 256, 0, stream>>>(er, start, cnt, dis, x, TxH, N);
    k_gemm1<<<(N + 3) / 4, 256, 0, stream>>>(x, TxH, W1, b1, N);
    k_stats<<<256, 256, 0, stream>>>(TxH, stats, N);
    k_prep<<<1, 64, 0, stream>>>(stats, gamma, beta, W2, b2, linW, linb,
                                 scale, shift, u0, u1, c0, N);
    k_node<<<(N + 3) / 4, 256, 0, stream>>>(TxH, scale, shift, u0, u1, a, t, N);
    k_gather2<<<(N + 255) / 256, 256, 0, stream>>>(er, start, cnt, dis, t, a, s2, N);
    k_pool2<<<G, 256, 0, stream>>>(s2, batch, c0, linb, out, N);
}

// Round 3
// 234.407 us; speedup vs baseline: 2.3727x; 1.1781x over previous
//
#include <hip/hip_runtime.h>

#define HDIM 64

// ---------------- small helpers ----------------

__device__ __forceinline__ int lbound(const int* __restrict__ b, int n, int v) {
    int lo = 0, hi = n;
    while (lo < hi) { int m = (lo + hi) >> 1; if (b[m] < v) lo = m + 1; else hi = m; }
    return lo;
}

// ---------------- kernels ----------------

// Histogram + rank: deg by row; rank[e] = running count of col (for direct CSR fill).
__global__ void k_hist(const int* __restrict__ row, const int* __restrict__ col,
                       int* __restrict__ deg, int* __restrict__ cnt,
                       int* __restrict__ rank, int E) {
    int e = blockIdx.x * blockDim.x + threadIdx.x;
    if (e < E) {
        atomicAdd(&deg[row[e]], 1);
        rank[e] = atomicAdd(&cnt[col[e]], 1);
    }
}

// Exclusive scan of cnt, 2-level. Level 1: per-1024 block scan.
__global__ __launch_bounds__(1024) void k_scan1(const int* __restrict__ cnt,
                                                int* __restrict__ start,
                                                int* __restrict__ bsum, int n) {
    __shared__ int sh[1024];
    int i = blockIdx.x * 1024 + threadIdx.x;
    int v = (i < n) ? cnt[i] : 0;
    sh[threadIdx.x] = v;
    __syncthreads();
    for (int off = 1; off < 1024; off <<= 1) {
        int t = 0;
        if (threadIdx.x >= off) t = sh[threadIdx.x - off];
        __syncthreads();
        sh[threadIdx.x] += t;
        __syncthreads();
    }
    if (i < n) start[i] = sh[threadIdx.x] - v;   // exclusive within block
    if (threadIdx.x == 1023) bsum[blockIdx.x] = sh[1023];
}

// Level 2: one wave, shuffle exclusive scan over block sums (nb <= 64).
__global__ void k_scan2(int* __restrict__ bsum, int nb) {
    int lane = threadIdx.x;
    if (lane >= 64) return;
    int v = (lane < nb) ? bsum[lane] : 0;
    int incl = v;
    #pragma unroll
    for (int off = 1; off < 64; off <<= 1) {
        int u = __shfl_up(incl, off, 64);
        if (lane >= off) incl += u;
    }
    if (lane < nb) bsum[lane] = incl - v;
}

// Level 3: add block offsets; also dis = deg^-1/2 (fused elementwise).
__global__ void k_scan3(int* __restrict__ start, const int* __restrict__ bsum,
                        const int* __restrict__ deg, float* __restrict__ dis, int n) {
    int i = blockIdx.x * blockDim.x + threadIdx.x;
    if (i < n) {
        start[i] += bsum[i >> 10];
        int d = deg[i];
        dis[i] = d > 0 ? rsqrtf((float)d) : 0.0f;
    }
}

// Fill CSR with precomputed ranks: pure scattered write, no atomics.
__global__ void k_fill(const int* __restrict__ row, const int* __restrict__ col,
                       const int* __restrict__ start, const int* __restrict__ rank,
                       int* __restrict__ er, int E) {
    int e = blockIdx.x * blockDim.x + threadIdx.x;
    if (e < E) er[start[col[e]] + rank[e]] = row[e];
}

// Gather 1: Tx[i][:] = sum over in-edges of (-dis[r]*dis[i]) * x[r][:]
// One 64-lane wave per node; 4-way unrolled for load ILP.
__global__ __launch_bounds__(256) void k_gather1(const int* __restrict__ er,
                                                 const int* __restrict__ start,
                                                 const int* __restrict__ cnt,
                                                 const float* __restrict__ dis,
                                                 const float* __restrict__ x,
                                                 float* __restrict__ Tx, int n) {
    int i = blockIdx.x * 4 + (threadIdx.x >> 6);
    if (i >= n) return;
    int lane = threadIdx.x & 63;
    int s = start[i], nd = cnt[i];
    float di = dis[i];
    float acc = 0.f;
    int k = 0;
    for (; k + 3 < nd; k += 4) {
        int r0 = er[s + k], r1 = er[s + k + 1], r2 = er[s + k + 2], r3 = er[s + k + 3];
        float w0 = -dis[r0] * di, w1 = -dis[r1] * di;
        float w2 = -dis[r2] * di, w3 = -dis[r3] * di;
        float v0 = x[(size_t)r0 * HDIM + lane];
        float v1 = x[(size_t)r1 * HDIM + lane];
        float v2 = x[(size_t)r2 * HDIM + lane];
        float v3 = x[(size_t)r3 * HDIM + lane];
        acc = fmaf(w0, v0, acc);
        acc = fmaf(w1, v1, acc);
        acc = fmaf(w2, v2, acc);
        acc = fmaf(w3, v3, acc);
    }
    for (; k < nd; ++k) {
        int r0 = er[s + k];
        acc = fmaf(-dis[r0] * di, x[(size_t)r0 * HDIM + lane], acc);
    }
    Tx[(size_t)i * HDIM + lane] = acc;
}

// h = x@W1[0] + Tx1@W1[1] + b1, in-place over Tx1. Grid-stride: W1 loaded
// once per block (1024 blocks -> 32 MB of W traffic vs 400 MB at 1 block/4 rows).
__global__ __launch_bounds__(256) void k_gemm1(const float* __restrict__ x,
                                               float* __restrict__ TxH,
                                               const float* __restrict__ W1,
                                               const float* __restrict__ b1, int n) {
    __shared__ float Ws[2 * HDIM * HDIM];       // 32 KB
    __shared__ float xs[4][HDIM];
    __shared__ float ts[4][HDIM];
    int tid = threadIdx.x;
    for (int idx = tid; idx < 2 * HDIM * HDIM; idx += 256) Ws[idx] = W1[idx];

    int rr = tid >> 6;
    int j  = tid & 63;
    float bj = b1[j];
    const float* w0 = Ws;
    const float* w1 = Ws + HDIM * HDIM;

    for (int base = blockIdx.x * 4; base < n; base += gridDim.x * 4) {
        int r = base + rr;
        __syncthreads();                 // protect previous iteration's LDS reads
        if (r < n) {
            xs[rr][j] = x[(size_t)r * HDIM + j];
            ts[rr][j] = TxH[(size_t)r * HDIM + j];
        }
        __syncthreads();
        if (r < n) {
            float acc = bj;
            #pragma unroll 8
            for (int k = 0; k < HDIM; ++k) {
                acc = fmaf(xs[rr][k], w0[k * HDIM + j], acc);
                acc = fmaf(ts[rr][k], w1[k * HDIM + j], acc);
            }
            TxH[(size_t)r * HDIM + j] = acc;
        }
    }
}

// Column sums / sums of squares over h (N x 64)
__global__ __launch_bounds__(256) void k_stats(const float* __restrict__ h,
                                               float* __restrict__ stats, int n) {
    int j  = threadIdx.x & 63;
    int rg = threadIdx.x >> 6;
    float s = 0.f, ss = 0.f;
    for (int r = blockIdx.x * 4 + rg; r < n; r += gridDim.x * 4) {
        float v = h[(size_t)r * HDIM + j];
        s += v;
        ss = fmaf(v, v, ss);
    }
    __shared__ float red[2][4][HDIM];
    red[0][rg][j] = s;
    red[1][rg][j] = ss;
    __syncthreads();
    if (rg == 0) {
        s  = red[0][0][j] + red[0][1][j] + red[0][2][j] + red[0][3][j];
        ss = red[1][0][j] + red[1][1][j] + red[1][2][j] + red[1][3][j];
        atomicAdd(&stats[j], s);
        atomicAdd(&stats[64 + j], ss);
    }
}

// BN scale/shift, u0 = W2[0]@linW, u1 = W2[1]@linW, c0 = b2.linW + linb
__global__ void k_prep(const float* __restrict__ stats,
                       const float* __restrict__ gamma, const float* __restrict__ beta,
                       const float* __restrict__ W2, const float* __restrict__ b2,
                       const float* __restrict__ linW, const float* __restrict__ linb,
                       float* __restrict__ scale, float* __restrict__ shift,
                       float* __restrict__ u0, float* __restrict__ u1,
                       float* __restrict__ c0, int n) {
    int k = threadIdx.x;
    if (k >= HDIM) return;
    float inv_n = 1.0f / (float)n;
    float mu  = stats[k] * inv_n;
    float var = stats[64 + k] * inv_n - mu * mu;
    float rs  = rsqrtf(var + 1e-5f);
    float sc  = rs * gamma[k];
    scale[k] = sc;
    shift[k] = beta[k] - mu * sc;
    float a0 = 0.f, a1 = 0.f;
    #pragma unroll 8
    for (int j = 0; j < HDIM; ++j) {
        float lw = linW[j];
        a0 = fmaf(W2[k * HDIM + j], lw, a0);
        a1 = fmaf(W2[HDIM * HDIM + k * HDIM + j], lw, a1);
    }
    u0[k] = a0;
    u1[k] = a1;
    if (k == 0) {
        float c = linb[0];
        for (int j = 0; j < HDIM; ++j) c = fmaf(b2[j], linW[j], c);
        c0[0] = c;
    }
}

// Per node: BN + LeakyReLU, a[i]=y.u0, t[i]=y.u1 (wave shuffle reduce).
__global__ __launch_bounds__(256) void k_node(const float* __restrict__ h,
                                              const float* __restrict__ scale,
                                              const float* __restrict__ shift,
                                              const float* __restrict__ u0,
                                              const float* __restrict__ u1,
                                              float* __restrict__ a, float* __restrict__ t,
                                              int n) {
    int i = blockIdx.x * 4 + (threadIdx.x >> 6);
    if (i >= n) return;
    int j = threadIdx.x & 63;
    float v = fmaf(h[(size_t)i * HDIM + j], scale[j], shift[j]);
    v = v >= 0.f ? v : 0.01f * v;
    float p0 = v * u0[j];
    float p1 = v * u1[j];
    #pragma unroll
    for (int off = 32; off > 0; off >>= 1) {
        p0 += __shfl_xor(p0, off, 64);
        p1 += __shfl_xor(p1, off, 64);
    }
    if (j == 0) { a[i] = p0; t[i] = p1; }
}

// Gather 2 (scalar): s2[i] = a[i] + sum over in-edges of (-dis[r]*dis[i]) * t[r]
__global__ void k_gather2(const int* __restrict__ er, const int* __restrict__ start,
                          const int* __restrict__ cnt, const float* __restrict__ dis,
                          const float* __restrict__ t, const float* __restrict__ a,
                          float* __restrict__ s2, int n) {
    int i = blockIdx.x * blockDim.x + threadIdx.x;
    if (i >= n) return;
    int s = start[i], nd = cnt[i];
    float di = dis[i];
    float acc = a[i];
    int k = 0;
    for (; k + 1 < nd; k += 2) {
        int r0 = er[s + k], r1 = er[s + k + 1];
        float v0 = -dis[r0] * di * t[r0];
        float v1 = -dis[r1] * di * t[r1];
        acc += v0 + v1;
    }
    if (k < nd) {
        int r0 = er[s + k];
        acc = fmaf(-dis[r0] * di, t[r0], acc);
    }
    s2[i] = acc;
}

// Pool: one block per graph; batch is sorted -> binary search the range.
__global__ __launch_bounds__(256) void k_pool2(const float* __restrict__ s2,
                                               const int* __restrict__ batch,
                                               const float* __restrict__ c0,
                                               const float* __restrict__ linb,
                                               float* __restrict__ out, int n) {
    int g = blockIdx.x;
    int lo = lbound(batch, n, g);
    int hi = lbound(batch, n, g + 1);
    float s = 0.f;
    for (int i = lo + threadIdx.x; i < hi; i += 256) s += s2[i];
    __shared__ float red[256];
    red[threadIdx.x] = s;
    __syncthreads();
    for (int off = 128; off > 0; off >>= 1) {
        if (threadIdx.x < off) red[threadIdx.x] += red[threadIdx.x + off];
        __syncthreads();
    }
    if (threadIdx.x == 0) {
        int cntg = hi - lo;
        out[g] = cntg > 0 ? red[0] / (float)cntg + c0[0] : linb[0];
    }
}

// ---------------- launch ----------------

extern "C" void kernel_launch(void* const* d_in, const int* in_sizes, int n_in,
                              void* d_out, int out_size, void* d_ws, size_t ws_size,
                              hipStream_t stream) {
    const float* x     = (const float*)d_in[0];
    const int*   eidx  = (const int*)d_in[1];
    const int*   batch = (const int*)d_in[2];
    const float* W1    = (const float*)d_in[3];
    const float* b1    = (const float*)d_in[4];
    const float* W2    = (const float*)d_in[5];
    const float* b2    = (const float*)d_in[6];
    const float* gamma = (const float*)d_in[7];
    const float* beta  = (const float*)d_in[8];
    const float* linW  = (const float*)d_in[9];
    const float* linb  = (const float*)d_in[10];
    float* out = (float*)d_out;

    const int N = in_sizes[0] / HDIM;       // 50000
    const int E = in_sizes[1] / 2;          // 800000
    const int G = out_size;                 // 100
    const int NB = (N + 1023) / 1024;       // scan blocks (49 <= 64)

    const int* row = eidx;
    const int* col = eidx + E;

    // ---- workspace layout ----
    // zero-required region first: deg(N int) | cnt(N int) | stats(128 f)
    char* wsb = (char*)d_ws;
    int*   deg   = (int*)wsb;                 wsb += (size_t)N * 4;
    int*   cnt   = (int*)wsb;                 wsb += (size_t)N * 4;
    float* stats = (float*)wsb;               wsb += 128 * 4;
    size_t zero_bytes = (size_t)wsb - (size_t)d_ws;
    int*   start = (int*)wsb;                 wsb += (size_t)N * 4;
    int*   bsum  = (int*)wsb;                 wsb += (size_t)NB * 4 + 64;
    int*   er    = (int*)wsb;                 wsb += (size_t)E * 4;
    float* dis   = (float*)wsb;               wsb += (size_t)N * 4;
    float* a     = (float*)wsb;               wsb += (size_t)N * 4;
    float* t     = (float*)wsb;               wsb += (size_t)N * 4;
    float* s2    = (float*)wsb;               wsb += (size_t)N * 4;
    float* TxH   = (float*)wsb;               wsb += (size_t)N * HDIM * 4;
    float* scale = (float*)wsb;               wsb += HDIM * 4;
    float* shift = (float*)wsb;               wsb += HDIM * 4;
    float* u0    = (float*)wsb;               wsb += HDIM * 4;
    float* u1    = (float*)wsb;               wsb += HDIM * 4;
    float* c0    = (float*)wsb;               wsb += 64;

    // rank[] is only live between k_hist and k_fill; TxH is written after ->
    // overlay rank onto the TxH region (no extra workspace).
    int* rank = (int*)TxH;

    hipMemsetAsync(d_ws, 0, zero_bytes, stream);

    k_hist<<<(E + 255) / 256, 256, 0, stream>>>(row, col, deg, cnt, rank, E);
    k_scan1<<<NB, 1024, 0, stream>>>(cnt, start, bsum, N);
    k_scan2<<<1, 64, 0, stream>>>(bsum, NB);
    k_scan3<<<(N + 255) / 256, 256, 0, stream>>>(start, bsum, deg, dis, N);
    k_fill<<<(E + 255) / 256, 256, 0, stream>>>(row, col, start, rank, er, E);
    k_gather1<<<(N + 3) / 4, 256, 0, stream>>>(er, start, cnt, dis, x, TxH, N);
    k_gemm1<<<1024, 256, 0, stream>>>(x, TxH, W1, b1, N);
    k_stats<<<256, 256, 0, stream>>>(TxH, stats, N);
    k_prep<<<1, 64, 0, stream>>>(stats, gamma, beta, W2, b2, linW, linb,
                                 scale, shift, u0, u1, c0, N);
    k_node<<<(N + 3) / 4, 256, 0, stream>>>(TxH, scale, shift, u0, u1, a, t, N);
    k_gather2<<<(N + 255) / 256, 256, 0, stream>>>(er, start, cnt, dis, t, a, s2, N);
    k_pool2<<<G, 256, 0, stream>>>(s2, batch, c0, linb, out, N);
}